// Round 2
// baseline (648.649 us; speedup 1.0000x reference)
//
#include <hip/hip_runtime.h>

// SS2D_Mamba horizontal scan, fused: per-position 1x1-conv (GEMM) + sigmoid +
// sequential selective scan. B=8, C=256, H=96, W=96, fp32.
//
//   x[b][c][h][w]; row (b,c,h) = 96 contiguous floats.
//   params[n][w][o] = sigmoid(sum_k xs[n][w][k]*weight[o][k] + bias[o]),
//   o-split A/B/C/D; scan over w: h = a*h + b*x ; y = c*h + d*x (per n, c)
//
// One block per n = b*H+h (768 blocks = 3/CU), 256 threads, thread t owns
// channel c=t for the scan and input-channel k=t for staging. Weight
// pre-packed to wTI[k][c] = {W[c][k],W[c+256][k],W[c+512][k],W[c+768][k]}
// so each (thread,k) needs one coalesced 16B load. x staged per 24-w quarter
// into double-buffered LDS via global_load_lds(16B); GEMM reads x as
// broadcast ds_read_b128 (conflict-free). Params never touch global memory.

#define C_DIM 256
#define H_DIM 96
#define W_DIM 96
#define QW    24   // w positions per quarter
#define NQ    4    // quarters

typedef float f4 __attribute__((ext_vector_type(4)));

__device__ __forceinline__ float sigf(float z) {
  // sigmoid(z) = 1/(1 + 2^(-z*log2(e))); v_exp_f32 / v_rcp_f32 are ~1ulp.
  return __builtin_amdgcn_rcpf(1.0f + __builtin_amdgcn_exp2f(z * -1.44269504088896340736f));
}

// weight [1024][256] -> wTI[k][c] (f4 of the 4 param-type rows), bias -> bias4.
__global__ void pack_w(const float* __restrict__ w, const float* __restrict__ bias,
                       f4* __restrict__ wTI, f4* __restrict__ bias4)
{
  const int t = blockIdx.x * 256 + threadIdx.x;   // t = k*256 + c
  const int k = t >> 8;
  const int c = t & 255;
  f4 v;
  v[0] = w[(size_t)(c      ) * C_DIM + k];
  v[1] = w[(size_t)(c + 256) * C_DIM + k];
  v[2] = w[(size_t)(c + 512) * C_DIM + k];
  v[3] = w[(size_t)(c + 768) * C_DIM + k];
  wTI[t] = v;
  if (k == 0) {
    f4 bb;
    bb[0] = bias[c];
    bb[1] = bias[c + 256];
    bb[2] = bias[c + 512];
    bb[3] = bias[c + 768];
    bias4[c] = bb;
  }
}

__global__ __launch_bounds__(256, 3) void ss2d_main(
    const float* __restrict__ x, const f4* __restrict__ wTI,
    const f4* __restrict__ bias4, float* __restrict__ y)
{
  // lds[buf][plane*256 + chan]: plane p = w-chunk [4p..4p+3] of the quarter.
  // 2 * 6*256*16B = 48 KB -> 3 blocks/CU.
  __shared__ f4 lds[2][6 * 256];

  const int tid = threadIdx.x;
  const int nb  = blockIdx.x;          // n = b*H + h
  const int b   = nb / H_DIM;
  const int h   = nb - b * H_DIM;

  const size_t rowoff = ((size_t)(b * C_DIM + tid) * H_DIM + h) * W_DIM;
  const float* xrow = x + rowoff;      // channel tid's 96 floats for (b,h)
  float*       yrow = y + rowoff;

  const f4 bv = bias4[tid];
  float hstate = 0.0f;

  // Stage quarter q into buffer s: plane i, chan tid <- 16B of
  // x[b][tid][h][q*24+4i .. +3]. LDS dest must be wave-uniform (HW appends
  // lane*16); global src is per-lane. All offsets 16B-aligned (row = 384B).
  auto stage = [&](int s, int q) {
    const int wbase = tid & ~63;       // wave-uniform chan base
#pragma unroll
    for (int i = 0; i < 6; ++i) {
      const float* g = xrow + q * QW + i * 4;
      auto* l = (__attribute__((address_space(3))) void*)(
          (char*)(&lds[s][0]) + (size_t)(i * 256 + wbase) * 16);
      __builtin_amdgcn_global_load_lds(
          (const __attribute__((address_space(1))) void*)g, l, 16, 0, 0);
    }
  };

  stage(0, 0);

  for (int q = 0; q < NQ; ++q) {
    const int cur = q & 1;
    __syncthreads();                   // drains vmcnt -> stage(q) visible
    if (q < NQ - 1) stage(cur ^ 1, q + 1);  // next-quarter loads in flight

    // ---- GEMM: logits for 24 w-positions x 4 param types (channel tid) ----
    f4 acc[QW];
#pragma unroll
    for (int w = 0; w < QW; ++w) acc[w] = bv;

    const f4* ldsc = &lds[cur][0];
    const f4* wp   = wTI + tid;
#pragma unroll 4
    for (int k = 0; k < C_DIM; ++k) {
      const f4 wv = wp[(size_t)k * C_DIM];          // coalesced 16B/lane (L2)
#pragma unroll
      for (int p = 0; p < 6; ++p) {
        const f4 xq = ldsc[p * 256 + k];            // broadcast ds_read_b128
#pragma unroll
        for (int u = 0; u < 4; ++u) {
          acc[p * 4 + u] += xq[u] * wv;             // 4 v_fma_f32
        }
      }
    }

    // ---- sigmoid + selective scan over this quarter ----
    f4 xt[6];
#pragma unroll
    for (int p = 0; p < 6; ++p) xt[p] = ldsc[p * 256 + tid];  // own channel

    f4 yo[6];
#pragma unroll
    for (int w = 0; w < QW; ++w) {
      const f4 lg = acc[w];
      const float a  = sigf(lg[0]);
      const float bb = sigf(lg[1]);
      const float cc = sigf(lg[2]);
      const float dd = sigf(lg[3]);
      const float xv = xt[w >> 2][w & 3];
      hstate = a * hstate + bb * xv;
      yo[w >> 2][w & 3] = cc * hstate + dd * xv;
    }

    f4* yq = (f4*)(yrow + q * QW);     // 16B-aligned (rowoff%96==0, QW=96B)
#pragma unroll
    for (int i = 0; i < 6; ++i) yq[i] = yo[i];
  }
}

extern "C" void kernel_launch(void* const* d_in, const int* in_sizes, int n_in,
                              void* d_out, int out_size, void* d_ws, size_t ws_size,
                              hipStream_t stream)
{
  const float* x    = (const float*)d_in[0];
  const float* w    = (const float*)d_in[1];
  const float* bias = (const float*)d_in[2];
  float* y = (float*)d_out;

  f4* wTI   = (f4*)d_ws;                                              // 1 MB
  f4* bias4 = (f4*)((char*)d_ws + (size_t)C_DIM * C_DIM * sizeof(f4)); // 4 KB

  hipLaunchKernelGGL(pack_w, dim3(256), dim3(256), 0, stream, w, bias, wTI, bias4);
  hipLaunchKernelGGL(ss2d_main, dim3(8 * H_DIM), dim3(256), 0, stream,
                     x, wTI, bias4, y);
}